// Round 8
// baseline (391.018 us; speedup 1.0000x reference)
//
#include <hip/hip_runtime.h>

typedef _Float16 f16;
typedef _Float16 f16x2 __attribute__((ext_vector_type(2)));
typedef _Float16 f16x4 __attribute__((ext_vector_type(4)));
typedef _Float16 f16x8 __attribute__((ext_vector_type(8)));
typedef float    f32x4 __attribute__((ext_vector_type(4)));

#define ES 40    // padded fp16 row stride for enc rows (80B; 20 dwords -> conflict-spread)
#define NPTS 128 // points per block

// ws layout (f16 elements):
//   W1T [256][32]  @ 0       (k>=24 zero-padded)
//   W2T [256][256] @ 8192
//   W3T [256][256] @ 73728
//   WoT [16][256]  @ 139264  (outfeat>=3 zero-padded)
//   enc_pad [1M][40] @ 143360  (padded encode rows, f16)
#define ENC_OFF 143360
#define WS_NEED (2ull*ENC_OFF + 2ull*1048576ull*40ull)

#define GLOAD_LDS16(g, l) __builtin_amdgcn_global_load_lds( \
    (const __attribute__((address_space(1))) void*)(g), \
    (__attribute__((address_space(3))) void*)(l), 16, 0, 0)

// s_h layout: [point][feat] f16, row stride 512B, 16B-chunk XOR swizzle by (point&7).
__device__ __forceinline__ f16* hswz(f16* base, int p, int fbyte) {
  return (f16*)((char*)base + p * 512 + (fbyte ^ ((p & 7) << 4)));
}

// per-level scale = 4*1.61^l - 1
static __device__ const float c_scale[12] = {
  3.0f, 5.44f, 9.3684f, 15.693124f, 25.87592964f, 42.2702467204f,
  68.665097219844f, 111.16080652394884f, 179.5788985035576f,
  289.7320265907278f, 467.0785628110717f, 752.6064861258255f };
static __device__ const unsigned c_res[12] = {4,7,11,17,27,44,70,113,181,291,469,754};

// one hash-grid level: returns (e0,e1). EXACT same arithmetic as prior rounds.
__device__ __forceinline__ f16x2 enc_level(float2 xy, int l, const float* __restrict__ tables) {
  float s = c_scale[l];
  unsigned res = c_res[l];
  float px = __fadd_rn(__fmul_rn(xy.x, s), 0.5f);
  float py = __fadd_rn(__fmul_rn(xy.y, s), 0.5f);
  float fx = floorf(px), fy = floorf(py);
  float wx = px - fx, wy = py - fy;
  unsigned ix = (unsigned)fx, iy = (unsigned)fy;
  unsigned i00, i10, i01, i11;
  if (res * res <= 65536u) {           // dense (tight grid)
    unsigned rm = res - 1u;
    unsigned x0 = min(ix, rm), x1 = min(ix + 1u, rm);
    unsigned y0 = min(iy, rm), y1 = min(iy + 1u, rm);
    i00 = x0 + y0 * res; i10 = x1 + y0 * res;
    i01 = x0 + y1 * res; i11 = x1 + y1 * res;
  } else {                             // spatial hash
    unsigned h0 = iy * 2654435761u, h1 = (iy + 1u) * 2654435761u;
    i00 = (ix ^ h0) & 65535u;  i10 = ((ix + 1u) ^ h0) & 65535u;
    i01 = (ix ^ h1) & 65535u;  i11 = ((ix + 1u) ^ h1) & 65535u;
  }
  const float2* tb = (const float2*)(tables + l * 131072);
  float2 f00 = tb[i00], f10 = tb[i10], f01 = tb[i01], f11 = tb[i11];
  float w00 = (1.f - wx) * (1.f - wy), w10 = wx * (1.f - wy);
  float w01 = (1.f - wx) * wy,         w11 = wx * wy;
  float e0 = w00 * f00.x + w10 * f10.x + w01 * f01.x + w11 * f11.x;
  float e1 = w00 * f00.y + w10 * f10.y + w01 * f01.y + w11 * f11.y;
  f16x2 pk; pk[0] = (f16)e0; pk[1] = (f16)e1;
  return pk;
}

__global__ __launch_bounds__(256) void prep_weights(
    const float* __restrict__ W1, const float* __restrict__ W2,
    const float* __restrict__ W3, const float* __restrict__ Wo,
    f16* __restrict__ ws)
{
  int i = blockIdx.x * 256 + threadIdx.x;
  if (i < 8192) {
    int o = i >> 5, k = i & 31;
    ws[i] = (k < 24) ? (f16)W1[k * 256 + o] : (f16)0.0f;
  } else if (i < 73728) {
    int j = i - 8192; int o = j >> 8, k = j & 255;
    ws[i] = (f16)W2[k * 256 + o];
  } else if (i < 139264) {
    int j = i - 73728; int o = j >> 8, k = j & 255;
    ws[i] = (f16)W3[k * 256 + o];
  } else if (i < 143360) {
    int j = i - 139264; int o = j >> 8, k = j & 255;
    ws[i] = (o < 3) ? (f16)Wo[k * 3 + o] : (f16)0.0f;
  }
}

// standalone encode: 1 thread/point, writes padded [pt][40 f16] rows
__global__ __launch_bounds__(256) void encode_kernel(
    const float* __restrict__ x, const float* __restrict__ tables,
    f16* __restrict__ encp)
{
  int gp = blockIdx.x * 256 + threadIdx.x;
  float2 xy = ((const float2*)x)[gp];
  f16x8 c[5];
  #pragma unroll
  for (int ch = 0; ch < 5; ++ch)
    #pragma unroll
    for (int j = 0; j < 8; ++j) c[ch][j] = (f16)0.0f;
  #pragma unroll
  for (int l = 0; l < 12; ++l) {
    f16x2 e = enc_level(xy, l, tables);
    c[l >> 2][(l & 3) * 2 + 0] = e[0];
    c[l >> 2][(l & 3) * 2 + 1] = e[1];
  }
  f16* row = encp + (size_t)gp * ES;
  #pragma unroll
  for (int ch = 0; ch < 5; ++ch)
    *(f16x8*)(row + ch * 8) = c[ch];
}

// one 256->256 layer IN PLACE over 128 points (4 waves x 64 outfeats).
// cur0/cur1: preloaded W k-panels 0,1. bv: preloaded bias frags.
// Tail (ks=6,7) prefetches next layer's panels+bias (or out-layer A rows).
template<bool NEXT_OUT>
__device__ __forceinline__ void layer256_pipe(
    f16* __restrict__ h, const f16* __restrict__ WT,
    const f32x4* bv, f16x8* cur0, f16x8* cur1,
    const f16* __restrict__ WTn, const float* __restrict__ bn,
    f16x8* nxt0, f16x8* nxt1, f32x4* bvn, f16x8* aout,
    const int* vbase, const int* wbase, int w, int l15, int g)
{
  f32x4 acc[4][8];
  #pragma unroll
  for (int mt = 0; mt < 4; ++mt)
    #pragma unroll
    for (int nt = 0; nt < 8; ++nt) acc[mt][nt] = bv[mt];

  f16x8 abuf[3][4];
  #pragma unroll
  for (int mt = 0; mt < 4; ++mt) { abuf[0][mt] = cur0[mt]; abuf[1][mt] = cur1[mt]; }

  const char* hb = (const char*)h;
  #pragma unroll
  for (int ks = 0; ks < 8; ++ks) {
    if (ks < 6) {          // prefetch this layer's panel ks+2 (2-ahead)
      #pragma unroll
      for (int mt = 0; mt < 4; ++mt)
        abuf[(ks+2)%3][mt] = *(const f16x8*)(WT + (w*64 + mt*16 + l15)*256 + (ks+2)*32 + g*8);
    } else if (ks == 6) {  // prefetch next layer, panel 0 + bias
      if (NEXT_OUT) {
        #pragma unroll
        for (int q = 0; q < 4; ++q)
          aout[q] = *(const f16x8*)(WTn + l15*256 + q*32 + g*8);
      } else {
        #pragma unroll
        for (int mt = 0; mt < 4; ++mt)
          nxt0[mt] = *(const f16x8*)(WTn + (w*64 + mt*16 + l15)*256 + g*8);
        #pragma unroll
        for (int mt = 0; mt < 4; ++mt)
          bvn[mt] = *(const f32x4*)(bn + w*64 + mt*16 + g*4);
      }
    } else {               // ks==7: next layer, panel 1
      if (NEXT_OUT) {
        #pragma unroll
        for (int q = 0; q < 4; ++q)
          aout[4+q] = *(const f16x8*)(WTn + l15*256 + (4+q)*32 + g*8);
      } else {
        #pragma unroll
        for (int mt = 0; mt < 4; ++mt)
          nxt1[mt] = *(const f16x8*)(WTn + (w*64 + mt*16 + l15)*256 + 32 + g*8);
      }
    }
    #pragma unroll
    for (int nt = 0; nt < 8; ++nt) {
      f16x8 b = *(const f16x8*)(hb + vbase[ks] + nt*8192);
      #pragma unroll
      for (int mt = 0; mt < 4; ++mt)
        acc[mt][nt] = __builtin_amdgcn_mfma_f32_16x16x32_f16(abuf[ks%3][mt], b, acc[mt][nt], 0, 0, 0);
    }
  }
  __syncthreads();   // all waves finished READING h
  #pragma unroll
  for (int mt = 0; mt < 4; ++mt) {
    #pragma unroll
    for (int nt = 0; nt < 8; ++nt) {
      f16x4 hv;
      #pragma unroll
      for (int r = 0; r < 4; ++r)
        hv[r] = (f16)fmaxf(acc[mt][nt][r], 0.0f);
      *(f16x4*)((char*)h + wbase[mt] + nt*8192) = hv;
    }
  }
  __syncthreads();   // h fully written for next consumer
}

// shared MLP body: layers 1-3 + out layer. s_enc must hold padded enc rows.
__device__ __forceinline__ void mlp_body(
    f16* s_enc, f16* s_h, const f16* ws,
    const float* b1, const float* b2, const float* b3, const float* bo,
    float* out, int blk, int w, int l15, int g,
    f16x8* a1, f16x8* pn0, f16x8* pn1, f32x4* bvA, f32x4* bvB,
    const int* vbase, const int* wbase)
{
  const f16* W3T = ws + 73728;
  const f16* WoT = ws + 139264;
  float bo0 = bo[0], bo1 = bo[1], bo2 = bo[2];

  // ---------------- layer 1: enc(128x32) -> s_h (128x256) ----------------
  {
    f32x4 acc[4][8];
    #pragma unroll
    for (int mt = 0; mt < 4; ++mt)
      #pragma unroll
      for (int nt = 0; nt < 8; ++nt) acc[mt][nt] = bvA[mt];
    #pragma unroll
    for (int nt = 0; nt < 8; ++nt) {
      f16x8 b = *(const f16x8*)(&s_enc[(nt*16 + l15) * ES + g*8]);
      #pragma unroll
      for (int mt = 0; mt < 4; ++mt)
        acc[mt][nt] = __builtin_amdgcn_mfma_f32_16x16x32_f16(a1[mt], b, acc[mt][nt], 0, 0, 0);
    }
    #pragma unroll
    for (int mt = 0; mt < 4; ++mt) {
      #pragma unroll
      for (int nt = 0; nt < 8; ++nt) {
        f16x4 hv;
        #pragma unroll
        for (int r = 0; r < 4; ++r)
          hv[r] = (f16)fmaxf(acc[mt][nt][r], 0.0f);
        *(f16x4*)((char*)s_h + wbase[mt] + nt*8192) = hv;
      }
    }
  }
  __syncthreads();

  f16x8 qn0[4], qn1[4], aout[8];
  f32x4 bvC[4];
  const f16* W2T = ws + 8192;
  layer256_pipe<false>(s_h, W2T, bvB, pn0, pn1, W3T, b3, qn0, qn1, bvC, aout,
                       vbase, wbase, w, l15, g);
  layer256_pipe<true >(s_h, W3T, bvC, qn0, qn1, WoT, nullptr, pn0, pn1, bvC, aout,
                       vbase, wbase, w, l15, g);

  // ---------------- output layer: wave w -> point-tiles 2w, 2w+1 ----------------
  {
    f32x4 acc0 = (f32x4)0.0f, acc1 = (f32x4)0.0f;
    const char* hb = (const char*)s_h;
    #pragma unroll
    for (int ks = 0; ks < 8; ++ks) {
      f16x8 b0 = *(const f16x8*)(hb + vbase[ks] + (2*w+0)*8192);
      f16x8 b1v = *(const f16x8*)(hb + vbase[ks] + (2*w+1)*8192);
      acc0 = __builtin_amdgcn_mfma_f32_16x16x32_f16(aout[ks], b0, acc0, 0, 0, 0);
      acc1 = __builtin_amdgcn_mfma_f32_16x16x32_f16(aout[ks], b1v, acc1, 0, 0, 0);
    }
    if (g == 0) {
      int gp0 = blk * NPTS + (2*w+0) * 16 + l15;
      int gp1 = blk * NPTS + (2*w+1) * 16 + l15;
      out[gp0 * 3 + 0] = acc0[0] + bo0;
      out[gp0 * 3 + 1] = acc0[1] + bo1;
      out[gp0 * 3 + 2] = acc0[2] + bo2;
      out[gp1 * 3 + 0] = acc1[0] + bo0;
      out[gp1 * 3 + 1] = acc1[1] + bo1;
      out[gp1 * 3 + 2] = acc1[2] + bo2;
    }
  }
}

// split-path main kernel: enc rows staged global->LDS, zero encode work
__global__ __launch_bounds__(256, 2) void hashmlp_main(
    const f16* __restrict__ encp,
    const float* __restrict__ b1, const float* __restrict__ b2,
    const float* __restrict__ b3, const float* __restrict__ bo,
    const f16* __restrict__ ws, float* __restrict__ out)
{
  __shared__ __align__(16) f16 s_enc[NPTS * ES];   // 10240 B = 640 x 16B
  __shared__ __align__(16) f16 s_h[NPTS * 256];

  const int tid = threadIdx.x;
  const int blk = blockIdx.x;
  const int w = tid >> 6, lane = tid & 63;
  const int l15 = lane & 15, g = lane >> 4;

  // -------- stage enc rows: 640 16B chunks via global_load_lds --------
  {
    const char* gsrc = (const char*)(encp) + (size_t)blk * (NPTS * ES * 2);
    char* lb = (char*)s_enc;
    GLOAD_LDS16(gsrc + (0*256 + w*64 + lane)*16, lb + (0*256 + w*64)*16);
    GLOAD_LDS16(gsrc + (1*256 + w*64 + lane)*16, lb + (1*256 + w*64)*16);
    if (w < 2)
      GLOAD_LDS16(gsrc + (512 + w*64 + lane)*16, lb + (512 + w*64)*16);
  }

  const f16* W1T = ws;
  const f16* W2T = ws + 8192;

  // -------- early prefetch: W1 frags, W2 panels 0/1, biases --------
  f16x8 a1[4], pn0[4], pn1[4];
  f32x4 bvA[4], bvB[4];
  #pragma unroll
  for (int mt = 0; mt < 4; ++mt) {
    a1[mt]  = *(const f16x8*)(W1T + (w*64 + mt*16 + l15)*32 + g*8);
    pn0[mt] = *(const f16x8*)(W2T + (w*64 + mt*16 + l15)*256 + g*8);
    pn1[mt] = *(const f16x8*)(W2T + (w*64 + mt*16 + l15)*256 + 32 + g*8);
    bvA[mt] = *(const f32x4*)(b1 + w*64 + mt*16 + g*4);
    bvB[mt] = *(const f32x4*)(b2 + w*64 + mt*16 + g*4);
  }

  int vbase[8], wbase[4];
  {
    int K = (l15 & 7) << 4;
    #pragma unroll
    for (int ks = 0; ks < 8; ++ks)
      vbase[ks] = l15*512 + ((ks*64 + g*16) ^ K);
    #pragma unroll
    for (int mt = 0; mt < 4; ++mt)
      wbase[mt] = l15*512 + (((w*64 + mt*16 + g*4)*2) ^ K);
  }

  __syncthreads();   // vmcnt(0) drain: enc staging complete, visible to all

  mlp_body(s_enc, s_h, ws, b1, b2, b3, bo, out, blk, w, l15, g,
           a1, pn0, pn1, bvA, bvB, vbase, wbase);
}

// fallback monolithic kernel (R6 structure) for small-ws harnesses
__global__ __launch_bounds__(256, 2) void hashmlp_mono(
    const float* __restrict__ x, const float* __restrict__ tables,
    const float* __restrict__ b1, const float* __restrict__ b2,
    const float* __restrict__ b3, const float* __restrict__ bo,
    const f16* __restrict__ ws, float* __restrict__ out)
{
  __shared__ __align__(16) f16 s_enc[NPTS * ES];
  __shared__ __align__(16) f16 s_h[NPTS * 256];

  const int tid = threadIdx.x;
  const int blk = blockIdx.x;
  const int w = tid >> 6, lane = tid & 63;
  const int l15 = lane & 15, g = lane >> 4;

  const f16* W1T = ws;
  const f16* W2T = ws + 8192;

  f16x8 a1[4], pn0[4], pn1[4];
  f32x4 bvA[4], bvB[4];
  #pragma unroll
  for (int mt = 0; mt < 4; ++mt) {
    a1[mt]  = *(const f16x8*)(W1T + (w*64 + mt*16 + l15)*32 + g*8);
    pn0[mt] = *(const f16x8*)(W2T + (w*64 + mt*16 + l15)*256 + g*8);
    pn1[mt] = *(const f16x8*)(W2T + (w*64 + mt*16 + l15)*256 + 32 + g*8);
    bvA[mt] = *(const f32x4*)(b1 + w*64 + mt*16 + g*4);
    bvB[mt] = *(const f32x4*)(b2 + w*64 + mt*16 + g*4);
  }

  int vbase[8], wbase[4];
  {
    int K = (l15 & 7) << 4;
    #pragma unroll
    for (int ks = 0; ks < 8; ++ks)
      vbase[ks] = l15*512 + ((ks*64 + g*16) ^ K);
    #pragma unroll
    for (int mt = 0; mt < 4; ++mt)
      wbase[mt] = l15*512 + (((w*64 + mt*16 + g*4)*2) ^ K);
  }

  // encode: 2 threads/point, 6 levels each
  {
    int p = tid >> 1, sub = tid & 1;
    int gp = blk * NPTS + p;
    float2 xy = ((const float2*)x)[gp];
    #pragma unroll
    for (int j = 0; j < 6; ++j) {
      int l = sub * 6 + j;
      f16x2 pk = enc_level(xy, l, tables);
      *(f16x2*)(&s_enc[p * ES + l * 2]) = pk;
    }
    f16x4 z; z[0] = (f16)0.0f; z[1] = (f16)0.0f; z[2] = (f16)0.0f; z[3] = (f16)0.0f;
    *(f16x4*)(&s_enc[p * ES + 24 + sub * 4]) = z;
  }
  __syncthreads();

  mlp_body(s_enc, s_h, ws, b1, b2, b3, bo, out, blk, w, l15, g,
           a1, pn0, pn1, bvA, bvB, vbase, wbase);
}

extern "C" void kernel_launch(void* const* d_in, const int* in_sizes, int n_in,
                              void* d_out, int out_size, void* d_ws, size_t ws_size,
                              hipStream_t stream) {
  const float* x  = (const float*)d_in[0];
  const float* tb = (const float*)d_in[1];
  const float* W1 = (const float*)d_in[2];
  const float* b1 = (const float*)d_in[3];
  const float* W2 = (const float*)d_in[4];
  const float* b2 = (const float*)d_in[5];
  const float* W3 = (const float*)d_in[6];
  const float* b3 = (const float*)d_in[7];
  const float* Wo = (const float*)d_in[8];
  const float* bo = (const float*)d_in[9];
  f16* ws = (f16*)d_ws;

  prep_weights<<<560, 256, 0, stream>>>(W1, W2, W3, Wo, ws);
  if (ws_size >= WS_NEED) {
    f16* encp = ws + ENC_OFF;
    encode_kernel<<<4096, 256, 0, stream>>>(x, tb, encp);
    hashmlp_main<<<8192, 256, 0, stream>>>(encp, b1, b2, b3, bo, ws, (float*)d_out);
  } else {
    hashmlp_mono<<<8192, 256, 0, stream>>>(x, tb, b1, b2, b3, bo, ws, (float*)d_out);
  }
}

// Round 9
// 353.740 us; speedup vs baseline: 1.1054x; 1.1054x over previous
//
#include <hip/hip_runtime.h>

typedef _Float16 f16;
typedef _Float16 f16x2 __attribute__((ext_vector_type(2)));
typedef _Float16 f16x4 __attribute__((ext_vector_type(4)));
typedef _Float16 f16x8 __attribute__((ext_vector_type(8)));
typedef float    f32x4 __attribute__((ext_vector_type(4)));

#define ES 40    // padded fp16 row stride for enc buffer (80B)
#define NPTS 128 // points per block

// per-level scale = 4*1.61^l - 1
static __device__ const float c_scale[12] = {
  3.0f, 5.44f, 9.3684f, 15.693124f, 25.87592964f, 42.2702467204f,
  68.665097219844f, 111.16080652394884f, 179.5788985035576f,
  289.7320265907278f, 467.0785628110717f, 752.6064861258255f };
static __device__ const unsigned c_res[12] = {4,7,11,17,27,44,70,113,181,291,469,754};

// ws layout (f16 elements):
//   W1T [256][32]  @ 0       (k>=24 zero-padded)
//   W2T [256][256] @ 8192
//   W3T [256][256] @ 73728
//   WoT [16][256]  @ 139264  (outfeat>=3 zero-padded)
__global__ __launch_bounds__(256) void prep_weights(
    const float* __restrict__ W1, const float* __restrict__ W2,
    const float* __restrict__ W3, const float* __restrict__ Wo,
    f16* __restrict__ ws)
{
  int i = blockIdx.x * 256 + threadIdx.x;
  if (i < 8192) {
    int o = i >> 5, k = i & 31;
    ws[i] = (k < 24) ? (f16)W1[k * 256 + o] : (f16)0.0f;
  } else if (i < 73728) {
    int j = i - 8192; int o = j >> 8, k = j & 255;
    ws[i] = (f16)W2[k * 256 + o];
  } else if (i < 139264) {
    int j = i - 73728; int o = j >> 8, k = j & 255;
    ws[i] = (f16)W3[k * 256 + o];
  } else if (i < 143360) {
    int j = i - 139264; int o = j >> 8, k = j & 255;
    ws[i] = (o < 3) ? (f16)Wo[k * 3 + o] : (f16)0.0f;
  }
}

// dense level (res*res <= 65536): the two x-corners are ADJACENT table entries,
// so one 16B load per y-row fetches both (f_x0, f_x0+1). Clamp edge (ix>=rm)
// handled by select — arithmetically identical to the reference.
// NOTE: entries are 8B-aligned; global_load_dwordx4 at dword alignment is
// legal on CDNA (the 16B-aligned vector type just selects the opcode).
__device__ __forceinline__ f16x2 enc_level_dense(
    float2 xy, float s, unsigned res, const float* __restrict__ tbl)
{
  float px = __fadd_rn(__fmul_rn(xy.x, s), 0.5f);
  float py = __fadd_rn(__fmul_rn(xy.y, s), 0.5f);
  float fx = floorf(px), fy = floorf(py);
  float wx = px - fx, wy = py - fy;
  unsigned ix = (unsigned)fx, iy = (unsigned)fy;
  unsigned rm = res - 1u;
  unsigned x0 = min(ix, rm);
  unsigned y0 = min(iy, rm), y1 = min(iy + 1u, rm);
  bool xe = (ix >= rm);                       // then x1 == x0
  f32x4 r0 = *(const f32x4*)(tbl + (x0 + y0 * res) * 2);
  f32x4 r1 = *(const f32x4*)(tbl + (x0 + y1 * res) * 2);
  float f00x = r0[0], f00y = r0[1];
  float f10x = xe ? r0[0] : r0[2], f10y = xe ? r0[1] : r0[3];
  float f01x = r1[0], f01y = r1[1];
  float f11x = xe ? r1[0] : r1[2], f11y = xe ? r1[1] : r1[3];
  float w00 = (1.f - wx) * (1.f - wy), w10 = wx * (1.f - wy);
  float w01 = (1.f - wx) * wy,         w11 = wx * wy;
  float e0 = w00 * f00x + w10 * f10x + w01 * f01x + w11 * f11x;
  float e1 = w00 * f00y + w10 * f10y + w01 * f01y + w11 * f11y;
  f16x2 pk; pk[0] = (f16)e0; pk[1] = (f16)e1;
  return pk;
}

// hash level (levels 10,11): 4 scattered float2 gathers, as before
__device__ __forceinline__ f16x2 enc_level_hash(
    float2 xy, float s, const float* __restrict__ tbl)
{
  float px = __fadd_rn(__fmul_rn(xy.x, s), 0.5f);
  float py = __fadd_rn(__fmul_rn(xy.y, s), 0.5f);
  float fx = floorf(px), fy = floorf(py);
  float wx = px - fx, wy = py - fy;
  unsigned ix = (unsigned)fx, iy = (unsigned)fy;
  unsigned h0 = iy * 2654435761u, h1 = (iy + 1u) * 2654435761u;
  unsigned i00 = (ix ^ h0) & 65535u,  i10 = ((ix + 1u) ^ h0) & 65535u;
  unsigned i01 = (ix ^ h1) & 65535u,  i11 = ((ix + 1u) ^ h1) & 65535u;
  const float2* tb = (const float2*)tbl;
  float2 f00 = tb[i00], f10 = tb[i10], f01 = tb[i01], f11 = tb[i11];
  float w00 = (1.f - wx) * (1.f - wy), w10 = wx * (1.f - wy);
  float w01 = (1.f - wx) * wy,         w11 = wx * wy;
  float e0 = w00 * f00.x + w10 * f10.x + w01 * f01.x + w11 * f11.x;
  float e1 = w00 * f00.y + w10 * f10.y + w01 * f01.y + w11 * f11.y;
  f16x2 pk; pk[0] = (f16)e0; pk[1] = (f16)e1;
  return pk;
}

// one 256->256 layer IN PLACE over 128 points (4 waves x 64 outfeats).
// cur0/cur1: preloaded W k-panels 0,1. bv: preloaded bias frags.
// Tail (ks=6,7) prefetches next layer's panels+bias (or out-layer A rows).
template<bool NEXT_OUT>
__device__ __forceinline__ void layer256_pipe(
    f16* __restrict__ h, const f16* __restrict__ WT,
    const f32x4* bv, f16x8* cur0, f16x8* cur1,
    const f16* __restrict__ WTn, const float* __restrict__ bn,
    f16x8* nxt0, f16x8* nxt1, f32x4* bvn, f16x8* aout,
    const int* vbase, const int* wbase, int w, int l15, int g)
{
  f32x4 acc[4][8];
  #pragma unroll
  for (int mt = 0; mt < 4; ++mt)
    #pragma unroll
    for (int nt = 0; nt < 8; ++nt) acc[mt][nt] = bv[mt];

  f16x8 abuf[3][4];
  #pragma unroll
  for (int mt = 0; mt < 4; ++mt) { abuf[0][mt] = cur0[mt]; abuf[1][mt] = cur1[mt]; }

  const char* hb = (const char*)h;
  #pragma unroll
  for (int ks = 0; ks < 8; ++ks) {
    if (ks < 6) {          // prefetch this layer's panel ks+2 (2-ahead)
      #pragma unroll
      for (int mt = 0; mt < 4; ++mt)
        abuf[(ks+2)%3][mt] = *(const f16x8*)(WT + (w*64 + mt*16 + l15)*256 + (ks+2)*32 + g*8);
    } else if (ks == 6) {  // prefetch next layer, panel 0 + bias
      if (NEXT_OUT) {
        #pragma unroll
        for (int q = 0; q < 4; ++q)
          aout[q] = *(const f16x8*)(WTn + l15*256 + q*32 + g*8);
      } else {
        #pragma unroll
        for (int mt = 0; mt < 4; ++mt)
          nxt0[mt] = *(const f16x8*)(WTn + (w*64 + mt*16 + l15)*256 + g*8);
        #pragma unroll
        for (int mt = 0; mt < 4; ++mt)
          bvn[mt] = *(const f32x4*)(bn + w*64 + mt*16 + g*4);
      }
    } else {               // ks==7: next layer, panel 1
      if (NEXT_OUT) {
        #pragma unroll
        for (int q = 0; q < 4; ++q)
          aout[4+q] = *(const f16x8*)(WTn + l15*256 + (4+q)*32 + g*8);
      } else {
        #pragma unroll
        for (int mt = 0; mt < 4; ++mt)
          nxt1[mt] = *(const f16x8*)(WTn + (w*64 + mt*16 + l15)*256 + 32 + g*8);
      }
    }
    #pragma unroll
    for (int nt = 0; nt < 8; ++nt) {
      f16x8 b = *(const f16x8*)(hb + vbase[ks] + nt*8192);
      #pragma unroll
      for (int mt = 0; mt < 4; ++mt)
        acc[mt][nt] = __builtin_amdgcn_mfma_f32_16x16x32_f16(abuf[ks%3][mt], b, acc[mt][nt], 0, 0, 0);
    }
  }
  __syncthreads();   // all waves finished READING h
  #pragma unroll
  for (int mt = 0; mt < 4; ++mt) {
    #pragma unroll
    for (int nt = 0; nt < 8; ++nt) {
      f16x4 hv;
      #pragma unroll
      for (int r = 0; r < 4; ++r)
        hv[r] = (f16)fmaxf(acc[mt][nt][r], 0.0f);
      *(f16x4*)((char*)h + wbase[mt] + nt*8192) = hv;
    }
  }
  __syncthreads();   // h fully written for next consumer
}

__global__ __launch_bounds__(256, 2) void hashmlp_kernel(
    const float* __restrict__ x, const float* __restrict__ tables,
    const float* __restrict__ b1, const float* __restrict__ b2,
    const float* __restrict__ b3, const float* __restrict__ bo,
    const f16* __restrict__ ws, float* __restrict__ out)
{
  __shared__ __align__(16) f16 s_enc[NPTS * ES];
  __shared__ __align__(16) f16 s_h[NPTS * 256];

  const int tid = threadIdx.x;
  const int blk = blockIdx.x;
  const int w = tid >> 6, lane = tid & 63;
  const int l15 = lane & 15, g = lane >> 4;

  const f16* W1T = ws;
  const f16* W2T = ws + 8192;
  const f16* W3T = ws + 73728;
  const f16* WoT = ws + 139264;

  // ---------------- early prefetch: W1 frags, W2 panels 0/1, biases ----------------
  f16x8 a1[4], pn0[4], pn1[4];
  f32x4 bvA[4], bvB[4];
  #pragma unroll
  for (int mt = 0; mt < 4; ++mt) {
    a1[mt]  = *(const f16x8*)(W1T + (w*64 + mt*16 + l15)*32 + g*8);
    pn0[mt] = *(const f16x8*)(W2T + (w*64 + mt*16 + l15)*256 + g*8);
    pn1[mt] = *(const f16x8*)(W2T + (w*64 + mt*16 + l15)*256 + 32 + g*8);
    bvA[mt] = *(const f32x4*)(b1 + w*64 + mt*16 + g*4);
    bvB[mt] = *(const f32x4*)(b2 + w*64 + mt*16 + g*4);
  }
  float bo0 = bo[0], bo1 = bo[1], bo2 = bo[2];

  // per-thread swizzled LDS base addresses (bytes), computed once
  int vbase[8], wbase[4];
  {
    int K = (l15 & 7) << 4;
    #pragma unroll
    for (int ks = 0; ks < 8; ++ks)
      vbase[ks] = l15*512 + ((ks*64 + g*16) ^ K);
    #pragma unroll
    for (int mt = 0; mt < 4; ++mt)
      wbase[mt] = l15*512 + (((w*64 + mt*16 + g*4)*2) ^ K);
  }

  // ---------------- encode: 2 threads/point, interleaved levels l = 2j+sub ----------
  // j<5 -> both lanes dense (paired 16B corner loads); j==5 -> both lanes hash.
  // No intra-wave path divergence.
  {
    int p = tid >> 1, sub = tid & 1;
    int gp = blk * NPTS + p;
    float2 xy = ((const float2*)x)[gp];
    #pragma unroll
    for (int j = 0; j < 5; ++j) {
      int l = j * 2 + sub;
      f16x2 pk = enc_level_dense(xy, c_scale[l], c_res[l], tables + l * 131072);
      *(f16x2*)(&s_enc[p * ES + l * 2]) = pk;
    }
    {
      int l = 10 + sub;
      f16x2 pk = enc_level_hash(xy, c_scale[l], tables + l * 131072);
      *(f16x2*)(&s_enc[p * ES + l * 2]) = pk;
    }
    f16x4 z; z[0] = (f16)0.0f; z[1] = (f16)0.0f; z[2] = (f16)0.0f; z[3] = (f16)0.0f;
    *(f16x4*)(&s_enc[p * ES + 24 + sub * 4]) = z;   // zero-pad k=24..31
  }
  __syncthreads();

  // ---------------- layer 1: enc(128x32) -> s_h (128x256) ----------------
  {
    f32x4 acc[4][8];
    #pragma unroll
    for (int mt = 0; mt < 4; ++mt)
      #pragma unroll
      for (int nt = 0; nt < 8; ++nt) acc[mt][nt] = bvA[mt];
    #pragma unroll
    for (int nt = 0; nt < 8; ++nt) {
      f16x8 b = *(const f16x8*)(&s_enc[(nt*16 + l15) * ES + g*8]);
      #pragma unroll
      for (int mt = 0; mt < 4; ++mt)
        acc[mt][nt] = __builtin_amdgcn_mfma_f32_16x16x32_f16(a1[mt], b, acc[mt][nt], 0, 0, 0);
    }
    // writes to s_h (distinct from s_enc) -> no prior barrier needed
    #pragma unroll
    for (int mt = 0; mt < 4; ++mt) {
      #pragma unroll
      for (int nt = 0; nt < 8; ++nt) {
        f16x4 hv;
        #pragma unroll
        for (int r = 0; r < 4; ++r)
          hv[r] = (f16)fmaxf(acc[mt][nt][r], 0.0f);
        *(f16x4*)((char*)s_h + wbase[mt] + nt*8192) = hv;
      }
    }
  }
  __syncthreads();

  f16x8 qn0[4], qn1[4], aout[8];
  f32x4 bvC[4];
  // layer 2: uses pn0/pn1+bvB; tail prefetches W3 panels (qn*) + b3 (bvC)
  layer256_pipe<false>(s_h, W2T, bvB, pn0, pn1, W3T, b3, qn0, qn1, bvC, aout,
                       vbase, wbase, w, l15, g);
  // layer 3: uses qn0/qn1+bvC; tail prefetches out-layer A rows (aout)
  layer256_pipe<true >(s_h, W3T, bvC, qn0, qn1, WoT, nullptr, pn0, pn1, bvC, aout,
                       vbase, wbase, w, l15, g);

  // ---------------- output layer: wave w -> point-tiles 2w, 2w+1 ----------------
  {
    f32x4 acc0 = (f32x4)0.0f, acc1 = (f32x4)0.0f;
    const char* hb = (const char*)s_h;
    #pragma unroll
    for (int ks = 0; ks < 8; ++ks) {
      f16x8 b0 = *(const f16x8*)(hb + vbase[ks] + (2*w+0)*8192);
      f16x8 b1v = *(const f16x8*)(hb + vbase[ks] + (2*w+1)*8192);
      acc0 = __builtin_amdgcn_mfma_f32_16x16x32_f16(aout[ks], b0, acc0, 0, 0, 0);
      acc1 = __builtin_amdgcn_mfma_f32_16x16x32_f16(aout[ks], b1v, acc1, 0, 0, 0);
    }
    if (g == 0) {   // rows 0..3 live in g==0 regs; feats 0..2 valid
      int gp0 = blk * NPTS + (2*w+0) * 16 + l15;
      int gp1 = blk * NPTS + (2*w+1) * 16 + l15;
      out[gp0 * 3 + 0] = acc0[0] + bo0;
      out[gp0 * 3 + 1] = acc0[1] + bo1;
      out[gp0 * 3 + 2] = acc0[2] + bo2;
      out[gp1 * 3 + 0] = acc1[0] + bo0;
      out[gp1 * 3 + 1] = acc1[1] + bo1;
      out[gp1 * 3 + 2] = acc1[2] + bo2;
    }
  }
}

extern "C" void kernel_launch(void* const* d_in, const int* in_sizes, int n_in,
                              void* d_out, int out_size, void* d_ws, size_t ws_size,
                              hipStream_t stream) {
  const float* x  = (const float*)d_in[0];
  const float* tb = (const float*)d_in[1];
  const float* W1 = (const float*)d_in[2];
  const float* b1 = (const float*)d_in[3];
  const float* W2 = (const float*)d_in[4];
  const float* b2 = (const float*)d_in[5];
  const float* W3 = (const float*)d_in[6];
  const float* b3 = (const float*)d_in[7];
  const float* Wo = (const float*)d_in[8];
  const float* bo = (const float*)d_in[9];
  f16* ws = (f16*)d_ws;

  prep_weights<<<560, 256, 0, stream>>>(W1, W2, W3, Wo, ws);
  hashmlp_kernel<<<8192, 256, 0, stream>>>(x, tb, b1, b2, b3, bo, ws, (float*)d_out);
}